// Round 7
// baseline (652.966 us; speedup 1.0000x reference)
//
#include <hip/hip_runtime.h>
#include <hip/hip_bf16.h>

constexpr int N_NODES = 100000;
constexpr int N_REL   = 4;
constexpr int N_EDGES = 600000;
constexpr int MAXDEG  = 32;          // Poisson(6): P(deg>=32) ~ 7e-14 per node
constexpr int D       = 128;
constexpr int KTOT    = N_REL * D;   // 512 concat cols of A
constexpr int M_PAD   = 100096;      // 782 blocks * 128 rows
constexpr int NXCD    = 8;

constexpr int BLD_BLKS = (N_REL * N_EDGES) / 256;   // 9375
constexpr int XC_BLKS  = (N_NODES * D / 4) / 256;   // 12500
constexpr int WC_BLKS  = (N_REL * D * D) / 256;     // 256

typedef __attribute__((ext_vector_type(8))) short bf16x8;   // MFMA A/B frag (4 VGPRs)
typedef __attribute__((ext_vector_type(4))) float f32x4;    // MFMA C/D frag

static __device__ __forceinline__ unsigned short f2bf(float f) {
    union { float f; unsigned int u; } v; v.f = f;
    unsigned int r = (v.u + 0x7fffu + ((v.u >> 16) & 1u)) >> 16;  // RNE
    return (unsigned short)r;
}

static __device__ __forceinline__ unsigned xcc_id() {
    unsigned x;
    asm volatile("s_getreg_b32 %0, hwreg(HW_REG_XCC_ID)" : "=s"(x));
    return x & 7;
}

// ---------------------------------------------------------------------------
// 1) Fused build + casts.  Edge blocks push each edge onto a per-XCD linked
//    list for its dst (workgroup-scope atomicExch -> executed in local XCD L2,
//    correct because head8[x] is only touched from XCD x) and bump a per-XCD
//    outdeg partial.  next[] is indexed by e -> coalesced store.  No
//    device-scope atomics at all.  Cast blocks ride in the idle bandwidth.
// ---------------------------------------------------------------------------
__global__ __launch_bounds__(256) void build_fused(const int* __restrict__ edges,
                                                   int* __restrict__ head8,
                                                   int* __restrict__ next,
                                                   int* __restrict__ outdeg8,
                                                   const float* __restrict__ X,
                                                   unsigned short* __restrict__ Xb,
                                                   const float* __restrict__ W,
                                                   unsigned short* __restrict__ Wt) {
    int b = blockIdx.x;
    if (b < BLD_BLKS) {
        unsigned xcd = xcc_id();
        int t = b * 256 + threadIdx.x;
        int r = t / N_EDGES;
        int e = t - r * N_EDGES;
        int s = edges[(size_t)r * 2 * N_EDGES + e];
        int d = edges[(size_t)r * 2 * N_EDGES + N_EDGES + e];
        __hip_atomic_fetch_add(&outdeg8[(xcd * N_REL + r) * N_NODES + s], 1,
                               __ATOMIC_RELAXED, __HIP_MEMORY_SCOPE_WORKGROUP);
        int old = __hip_atomic_exchange(&head8[(xcd * N_REL + r) * N_NODES + d], e,
                                        __ATOMIC_RELAXED, __HIP_MEMORY_SCOPE_WORKGROUP);
        next[r * N_EDGES + e] = old;
    } else if (b < BLD_BLKS + XC_BLKS) {
        int t = (b - BLD_BLKS) * 256 + threadIdx.x;
        float4 v = ((const float4*)X)[t];
        union { unsigned short u[4]; uint2 d; } o;
        o.u[0] = f2bf(v.x); o.u[1] = f2bf(v.y); o.u[2] = f2bf(v.z); o.u[3] = f2bf(v.w);
        ((uint2*)Xb)[t] = o.d;
    } else {
        int t = (b - BLD_BLKS - XC_BLKS) * 256 + threadIdx.x;
        int r = t >> 14;
        int k = (t >> 7) & 127;
        int n = t & 127;
        Wt[(size_t)n * KTOT + r * D + k] = f2bf(W[t]);
    }
}

// ---------------------------------------------------------------------------
// 2) List walk: one thread per (rel, node).  Walks the 8 per-XCD chains
//    INTERLEAVED (8 independent loads in flight), materializes ELL esrc rows
//    + true indeg, and reduces the 8 outdeg partials.  All chain data
//    (head8 12.8MB + next 9.6MB + edge srcs) is L2/L3-resident.
// ---------------------------------------------------------------------------
__global__ __launch_bounds__(256) void listwalk(const int* __restrict__ head8,
                                                const int* __restrict__ next,
                                                const int* __restrict__ edges,
                                                int* __restrict__ esrc,
                                                int* __restrict__ indeg,
                                                const int* __restrict__ outdeg8,
                                                int* __restrict__ outdeg) {
    int d = blockIdx.x * 256 + threadIdx.x;
    int r = blockIdx.y;
    if (d >= N_NODES) return;

    int e[NXCD];
#pragma unroll
    for (int x = 0; x < NXCD; x++)
        e[x] = head8[(x * N_REL + r) * N_NODES + d];

    const int* srcarr = edges + (size_t)r * 2 * N_EDGES;
    const int* nx     = next + (size_t)r * N_EDGES;
    int* row = esrc + ((size_t)r * N_NODES + d) * MAXDEG;

    int cnt = 0;
    bool any = true;
    while (any) {
        any = false;
        int s[NXCD];
#pragma unroll
        for (int x = 0; x < NXCD; x++)          // issue all loads (independent)
            if (e[x] >= 0) { s[x] = srcarr[e[x]]; }
#pragma unroll
        for (int x = 0; x < NXCD; x++) {
            if (e[x] >= 0) {
                if (cnt < MAXDEG) row[cnt] = s[x];
                cnt++;
                e[x] = nx[e[x]];
                any = true;
            }
        }
    }
    indeg[r * N_NODES + d] = cnt;

    int od = 0;
#pragma unroll
    for (int x = 0; x < NXCD; x++)
        od += outdeg8[(x * N_REL + r) * N_NODES + d];
    outdeg[r * N_NODES + d] = od;
}

// ---------------------------------------------------------------------------
// 3) Fused 4-relation gather: one wave per dst node; the 4 relations' edge
//    loops interleaved -> 4 independent in-flight loads; random-read working
//    set is Xb (25.6 MB).
//    A[d][r*128+c] = bf16( rin_r[d] * sum_e rout_r[src_e] * Xb[src_e][c] )
// ---------------------------------------------------------------------------
__global__ __launch_bounds__(256) void gather_ell(const int* __restrict__ esrc,
                                                  const int* __restrict__ indeg,
                                                  const int* __restrict__ outdeg,
                                                  const unsigned int* __restrict__ Xb2,
                                                  unsigned int* __restrict__ A4) {
    int w    = threadIdx.x >> 6;
    int lane = threadIdx.x & 63;
    int d    = blockIdx.x * 4 + w;
    if (d >= N_NODES) return;

    int   n[N_REL];
    float rin[N_REL];
    int   s_l[N_REL];
    float c_l[N_REL];
#pragma unroll
    for (int r = 0; r < N_REL; r++) {
        int ind = indeg[r * N_NODES + d];
        n[r]   = ind > MAXDEG ? MAXDEG : ind;
        rin[r] = rsqrtf((float)(ind < 1 ? 1 : ind));
        s_l[r] = 0;
        c_l[r] = 0.f;
        if (lane < n[r]) {
            s_l[r] = esrc[((size_t)r * N_NODES + d) * MAXDEG + lane];
            int od = outdeg[r * N_NODES + s_l[r]];
            c_l[r] = rsqrtf((float)(od < 1 ? 1 : od));
        }
    }
    int nmax = max(max(n[0], n[1]), max(n[2], n[3]));

    float2 acc[N_REL];
#pragma unroll
    for (int r = 0; r < N_REL; r++) acc[r] = make_float2(0.f, 0.f);

    for (int i = 0; i < nmax; i++) {
        unsigned v[N_REL];
        float    c[N_REL];
#pragma unroll
        for (int r = 0; r < N_REL; r++) {
            int s = __shfl(s_l[r], i);
            c[r]  = __shfl(c_l[r], i);
            v[r]  = 0u;
            if (i < n[r])                   // wave-uniform branch
                v[r] = Xb2[(size_t)s * (D / 2) + lane];
        }
#pragma unroll
        for (int r = 0; r < N_REL; r++) {
            union { unsigned u; float f; } lo, hi;
            lo.u = v[r] << 16;
            hi.u = v[r] & 0xFFFF0000u;
            acc[r].x += c[r] * lo.f;
            acc[r].y += c[r] * hi.f;
        }
    }

#pragma unroll
    for (int r = 0; r < N_REL; r++) {
        unsigned lo = f2bf(rin[r] * acc[r].x);
        unsigned hi = f2bf(rin[r] * acc[r].y);
        A4[(size_t)d * (KTOT / 2) + r * (D / 2) + lane] = lo | (hi << 16);
    }
}

// ---------------------------------------------------------------------------
// 4) Final GEMM: Z[100K][128] = A[100K][512](bf16) @ Wt^T  via 16x16x32 MFMA.
// ---------------------------------------------------------------------------
__global__ __launch_bounds__(256) void gemm_mfma(const unsigned short* __restrict__ A,
                                                 const unsigned short* __restrict__ Wt,
                                                 float* __restrict__ Z) {
    int w    = threadIdx.x >> 6;
    int lane = threadIdx.x & 63;
    int l15  = lane & 15;
    int quad = lane >> 4;
    int row0 = blockIdx.x * 128 + w * 32;

    f32x4 acc[2][8];
#pragma unroll
    for (int m = 0; m < 2; m++)
#pragma unroll
        for (int j = 0; j < 8; j++) acc[m][j] = (f32x4){0.f, 0.f, 0.f, 0.f};

    for (int k0 = 0; k0 < KTOT; k0 += 32) {
        bf16x8 a[2];
#pragma unroll
        for (int m = 0; m < 2; m++)
            a[m] = *(const bf16x8*)(A + (size_t)(row0 + m * 16 + l15) * KTOT + k0 + quad * 8);
#pragma unroll
        for (int j = 0; j < 8; j++) {
            bf16x8 b = *(const bf16x8*)(Wt + (size_t)(j * 16 + l15) * KTOT + k0 + quad * 8);
            acc[0][j] = __builtin_amdgcn_mfma_f32_16x16x32_bf16(a[0], b, acc[0][j], 0, 0, 0);
            acc[1][j] = __builtin_amdgcn_mfma_f32_16x16x32_bf16(a[1], b, acc[1][j], 0, 0, 0);
        }
    }

    // C/D layout: col = lane&15, row = quad*4 + reg
#pragma unroll
    for (int m = 0; m < 2; m++)
#pragma unroll
        for (int reg = 0; reg < 4; reg++) {
            int row = row0 + m * 16 + quad * 4 + reg;
            if (row < N_NODES) {
#pragma unroll
                for (int j = 0; j < 8; j++)
                    Z[(size_t)row * D + j * 16 + l15] = acc[m][j][reg];
            }
        }
}

// ---------------------------------------------------------------------------
extern "C" void kernel_launch(void* const* d_in, const int* in_sizes, int n_in,
                              void* d_out, int out_size, void* d_ws, size_t ws_size,
                              hipStream_t stream) {
    const int*   edges = (const int*)d_in[0];
    const float* X     = (const float*)d_in[1];
    const float* W     = (const float*)d_in[2];
    float*       Z     = (float*)d_out;

    auto align256 = [](size_t x) { return (x + 255) & ~(size_t)255; };
    char* ws = (char*)d_ws;
    size_t off = 0;
    int* esrc          = (int*)(ws + off);            off = align256(off + (size_t)N_REL * N_NODES * MAXDEG * sizeof(int));
    unsigned short* Xb = (unsigned short*)(ws + off); off = align256(off + (size_t)N_NODES * D * sizeof(short));
    unsigned short* Wt = (unsigned short*)(ws + off); off = align256(off + (size_t)KTOT * D * sizeof(short));
    int* indeg         = (int*)(ws + off);            off = align256(off + (size_t)N_REL * N_NODES * sizeof(int));
    int* outdeg        = (int*)(ws + off);            off = align256(off + (size_t)N_REL * N_NODES * sizeof(int));
    unsigned short* A  = (unsigned short*)(ws + off); off = align256(off + (size_t)M_PAD * KTOT * sizeof(short));

    // Build-phase scratch aliases the A region (dead before gather writes A;
    // the aliased 35 MB lies inside gather's fully-written first 102.4 MB):
    int* head8   = (int*)A;                                   // [8][4][N] 12.8 MB
    int* outdeg8 = head8 + (size_t)NXCD * N_REL * N_NODES;    // [8][4][N] 12.8 MB
    int* next    = outdeg8 + (size_t)NXCD * N_REL * N_NODES;  // [4][E]     9.6 MB

    hipMemsetAsync(head8, 0xFF, (size_t)NXCD * N_REL * N_NODES * sizeof(int), stream);  // -1
    hipMemsetAsync(outdeg8, 0, (size_t)NXCD * N_REL * N_NODES * sizeof(int), stream);

    build_fused<<<BLD_BLKS + XC_BLKS + WC_BLKS, 256, 0, stream>>>(
        edges, head8, next, outdeg8, X, Xb, W, Wt);

    dim3 lwgrid((N_NODES + 255) / 256, N_REL);
    listwalk<<<lwgrid, 256, 0, stream>>>(head8, next, edges, esrc, indeg, outdeg8, outdeg);

    gather_ell<<<(N_NODES + 3) / 4, 256, 0, stream>>>(
        esrc, indeg, outdeg, (const unsigned int*)Xb, (unsigned int*)A);

    gemm_mfma<<<M_PAD / 128, 256, 0, stream>>>(A, Wt, Z);
}